// Round 3
// baseline (14210.336 us; speedup 1.0000x reference)
//
#include <hip/hip_runtime.h>
#include <cstdint>
#include <cstddef>

// Problem constants
#define Hh 2048
#define Vv 32000
#define Bb 16
#define Ss 256

typedef unsigned short ushort_t;
typedef unsigned int   uint_t;
typedef unsigned long long ull_t;

typedef __attribute__((ext_vector_type(8))) short short8;   // 8 x bf16 (4 VGPRs)
typedef __attribute__((ext_vector_type(4))) float f32x4;    // MFMA accumulator

// ---- workspace layout (bytes) ----
// Zbuf  : AGENT copy, 3 slots x [b16][h2048] bf16, parity in sign bits
// Y255  : [b][h] f32 final-step y
// ZbufF : FAST copy (XCD-L2 visibility), same layout as Zbuf
#define Z_OFF    0ull
#define Z_SLOT   ((size_t)Bb * Hh * 2)          // 64 KiB per slot
#define Z_BYTES  ((size_t)3 * Z_SLOT)
#define Y_OFF    (Z_OFF + Z_BYTES)
#define Y_BYTES  ((size_t)Bb * Hh * 4)
#define ZF_OFF   (Y_OFF + Y_BYTES)
#define ZF_BYTES ((size_t)3 * Z_SLOT)
#define WS_NEED  (ZF_OFF + ZF_BYTES)

// Protocol: the DATA is the flag (verified rounds 0-2).
//  - step k publishes z~^k to slot phys(k%3)=(3-k%3)%3, all bf16 sign bits
//    = k&1, to BOTH buffers (fast: plain store -> local XCD L2; agent: sc1
//    store -> MALL). Fire-and-forget.
//  - step k consumer spins on slot phys((k-1)%3) until sign bits ==(k-1)&1.
//    Stale slot data is exactly 3 steps old -> opposite parity; >=6-step
//    skew impossible (every WG consumes every group-WG's chunk each step).
//  - k=1: agent path (host-memset-scrubbed, ground truth).
//    k=2: agent path + validation: fast copy must byte-match agent truth
//         (bounded retries) else permanent per-thread agent fallback. This
//    makes the fast path safe even if the blockIdx%8->XCD mapping ever
//    fails: wrong co-location => mismatch => round-1 behavior.
//    k>=3: fast path (sc0 loads, L2-hit ~200cy) with bounded escape.
//  - in-kernel fast-buffer scrub (slots0,1=parity1, slot2=parity0) ordered
//    before the k=0 publish by the vmcnt-draining __syncthreads; consumers'
//    first fast poll of any producer is chain-guarded by having consumed
//    that producer's k=0/k-1 agent data => sees scrub-or-newer.
//  - lagged global max: mhat_k = mhat_{k-1} + log(max_h z~^{k-1}[c,h]),
//    derived bit-identically by every WG from the staged bf16 data.
#define LD_REL(p)     __hip_atomic_load((p), __ATOMIC_RELAXED, __HIP_MEMORY_SCOPE_AGENT)
#define ST_REL(p, v)  __hip_atomic_store((p), (v), __ATOMIC_RELAXED, __HIP_MEMORY_SCOPE_AGENT)

#define SGN64 0x8000800080008000ull
#define MAG64 0x7FFF7FFF7FFF7FFFull

__device__ __forceinline__ float b2f_u(uint_t u) {
  union { uint_t u; float f; } x; x.u = u; return x.f;
}
__device__ __forceinline__ ushort_t f2b(float f) {
  union { float f; uint_t u; } x; x.f = f;
  uint_t u = x.u;
  return (ushort_t)((u + 0x7FFFu + ((u >> 16) & 1u)) >> 16);   // RNE f32->bf16
}
__device__ __forceinline__ uint_t umaxu(uint_t a, uint_t b) { return a > b ? a : b; }
// packed 2 x u16 max (positive bf16 ordering == integer ordering)
__device__ __forceinline__ uint_t pkmax16(uint_t a, uint_t b) {
  uint_t lo = umaxu(a & 0xFFFFu, b & 0xFFFFu);
  uint_t hi = umaxu(a >> 16, b >> 16);
  return lo | (hi << 16);
}

// ---------------------------------------------------------------------------
// Persistent scan kernel. 256 WGs x 256 threads.
// 8 column-groups (g = blockIdx & 7) of 32 WGs; with blockIdx%8 -> XCD
// dispatch, each group occupies the 32 CUs of ONE XCD (fast-path locality).
// Group g owns batch columns {2g, 2g+1}. WG wl owns rows [wl*64, wl*64+64).
// K-SPLIT: wave wv owns K-chunk [wv*512, wv*512+512) of all 4 row-tiles;
// partials combined through LDS at barrier B2.
// ---------------------------------------------------------------------------
__global__ __launch_bounds__(256, 1) void hmm_persist(
    const float* __restrict__ alpha,
    const float* __restrict__ beta,
    const int*  __restrict__ ids,
    ushort_t* __restrict__ Zbuf,      // agent (MALL) copy
    ushort_t* __restrict__ ZbufF,     // fast (XCD-L2) copy
    float* __restrict__ Y255,
    float* __restrict__ out)
{
  const int w    = blockIdx.x;
  const int g    = w & 7;
  const int wl   = w >> 3;         // 0..31 within group -> row chunk
  const int c0   = g * 2;          // first batch column of group
  const int tid  = threadIdx.x;
  const int wv   = tid >> 6;       // wave 0..3 = K-chunk
  const int lane = tid & 63;
  const int lrow = lane & 15;
  const int quad = lane >> 4;

  __shared__ __align__(16) ushort_t zTf[2 * 2080];  // 2 cols x (2048+32 pad)
  __shared__ float ybuf[128];      // init only
  __shared__ float ipld[128];      // ip_rev[k]: [row][col], stride 2
  __shared__ uint_t redm[4];       // per-wave packed (c0max | c1max<<16)
  __shared__ __align__(16) float red[4][4][256];    // [tile][wave][lane*4]

  ull_t* ZbA = (ull_t*)Zbuf;
  ull_t* ZbF = (ull_t*)ZbufF;

  // ---- preload alpha A-fragments: rows wl*64+t*16+lrow, K=wv*512+kt*32 ----
  short8 afr[64];                  // [t*16 + kt]
  #pragma unroll
  for (int t = 0; t < 4; ++t) {
    #pragma unroll
    for (int kt = 0; kt < 16; ++kt) {
      const float* arow = alpha + (size_t)(wl * 64 + t * 16 + lrow) * Hh
                          + wv * 512 + kt * 32 + quad * 8;
      float4 f0 = *(const float4*)arow;
      float4 f1 = *(const float4*)(arow + 4);
      short8 fr;
      fr[0] = (short)f2b(f0.x); fr[1] = (short)f2b(f0.y);
      fr[2] = (short)f2b(f0.z); fr[3] = (short)f2b(f0.w);
      fr[4] = (short)f2b(f1.x); fr[5] = (short)f2b(f1.y);
      fr[6] = (short)f2b(f1.z); fr[7] = (short)f2b(f1.w);
      afr[t * 16 + kt] = fr;
    }
  }

  // ---- scrub FAST buffer (own granules, all 3 slots) ----
  // slot0,1 -> parity1 (SGN64), slot2 -> parity0 (0). Ordered before the
  // k=0 publish by the vmcnt(0)-draining __syncthreads below.
  if (tid < 96) {
    const int sl = tid >> 5, cc = (tid >> 4) & 1, gg = tid & 15;
    const ull_t v = (sl == 2) ? 0ull : SGN64;
    *(volatile ull_t*)(ZbF + (size_t)sl * 8192 + (size_t)(c0 + cc) * 512
                        + (wl * 16 + gg)) = v;
  }

  const int myc = tid & 1;                 // gather mapping for tid<128
  const int myr = wl * 64 + (tid >> 1);
  float ipreg = 0.f;

  // ---- init (k=0): y^0 = beta[:, ids[:,S-1]]; publish z~^0=exp(y^0) ----
  {
    if (tid < 128) {
      const int v = ids[(c0 + myc) * Ss + (Ss - 1)];
      float yv = beta[(size_t)myr * Vv + v];
      ybuf[tid] = yv;
      out[(size_t)myr * Bb + (c0 + myc)] = yv;   // ys[0][h][b]
    }
    __syncthreads();   // drains scrub stores; orders scrub < publish
    if (tid < 32) {
      const int c = tid >> 4, q = tid & 15;
      uint_t b0 = f2b(__expf(ybuf[(q * 4 + 0) * 2 + c]));
      uint_t b1 = f2b(__expf(ybuf[(q * 4 + 1) * 2 + c]));
      uint_t b2 = f2b(__expf(ybuf[(q * 4 + 2) * 2 + c]));
      uint_t b3 = f2b(__expf(ybuf[(q * 4 + 3) * 2 + c]));
      ull_t val = (ull_t)(b0 | (b1 << 16)) | ((ull_t)(b2 | (b3 << 16)) << 32);
      const size_t off = (size_t)(c0 + c) * 512 + (wl * 16 + q);  // slot0,par0
      *(volatile ull_t*)(ZbF + off) = val;
      ST_REL(ZbA + off, val);
    }
    if (tid < 128) {   // prefetch ip_rev[1]
      const int v1 = ids[(c0 + myc) * Ss + (Ss - 2)];
      ipreg = beta[(size_t)myr * Vv + v1];
    }
  }

  // per-thread constant granule offsets (col, h4): j0=(0,tid) j1=(0,tid+256)
  // j2=(1,tid) j3=(1,tid+256)
  const size_t go0 = (size_t)c0 * 512 + tid;
  const size_t go1 = (size_t)c0 * 512 + 256 + tid;
  const size_t go2 = (size_t)(c0 + 1) * 512 + tid;
  const size_t go3 = (size_t)(c0 + 1) * 512 + 256 + tid;

  float mprev = 0.f;               // mhat_{k-1} for col (lrow&1)
  bool agentOnly = false;          // sticky per-thread fallback
  const ushort_t* zbase = zTf + (lrow & 1) * 2080 + quad * 8;

  for (int k = 1; k < Ss; ++k) {
    const int   physR = (3 - ((k - 1) % 3)) % 3;
    const ull_t expS  = ((k - 1) & 1) ? SGN64 : 0ull;
    const size_t sb   = (size_t)physR * 8192;
    ull_t z0, z1, z2, z3;

    if (k <= 2 || agentOnly) {
      // ---- authoritative agent poll (round-1 verified path) ----
      z0 = LD_REL(ZbA + sb + go0); z1 = LD_REL(ZbA + sb + go1);
      z2 = LD_REL(ZbA + sb + go2); z3 = LD_REL(ZbA + sb + go3);
      while ((((z0 ^ expS) | (z1 ^ expS) | (z2 ^ expS) | (z3 ^ expS)) & SGN64) != 0ull) {
        if ((z0 & SGN64) != expS) z0 = LD_REL(ZbA + sb + go0);
        if ((z1 & SGN64) != expS) z1 = LD_REL(ZbA + sb + go1);
        if ((z2 & SGN64) != expS) z2 = LD_REL(ZbA + sb + go2);
        if ((z3 & SGN64) != expS) z3 = LD_REL(ZbA + sb + go3);
      }
      if (k == 2 && !agentOnly) {
        // ---- validate fast copies == agent truth (bounded) ----
        const ull_t* p0 = ZbF + sb + go0; const ull_t* p1 = ZbF + sb + go1;
        const ull_t* p2 = ZbF + sb + go2; const ull_t* p3 = ZbF + sb + go3;
        bool okf = false;
        for (int t = 0; t < 64 && !okf; ++t) {
          ull_t f0, f1, f2, f3;
          asm volatile(
            "global_load_dwordx2 %0, %4, off sc0\n\t"
            "global_load_dwordx2 %1, %5, off sc0\n\t"
            "global_load_dwordx2 %2, %6, off sc0\n\t"
            "global_load_dwordx2 %3, %7, off sc0\n\t"
            "s_waitcnt vmcnt(0)"
            : "=&v"(f0), "=&v"(f1), "=&v"(f2), "=&v"(f3)
            : "v"(p0), "v"(p1), "v"(p2), "v"(p3)
            : "memory");
          okf = (f0 == z0) & (f1 == z1) & (f2 == z2) & (f3 == z3);
        }
        if (!okf) agentOnly = true;   // not L2-co-located: round-1 behavior
      }
    } else {
      // ---- fast poll: sc0 loads (L1-bypass, local-L2 hit) ----
      const ull_t* p0 = ZbF + sb + go0; const ull_t* p1 = ZbF + sb + go1;
      const ull_t* p2 = ZbF + sb + go2; const ull_t* p3 = ZbF + sb + go3;
      int rounds = 0;
      for (;;) {
        asm volatile(
          "global_load_dwordx2 %0, %4, off sc0\n\t"
          "global_load_dwordx2 %1, %5, off sc0\n\t"
          "global_load_dwordx2 %2, %6, off sc0\n\t"
          "global_load_dwordx2 %3, %7, off sc0\n\t"
          "s_waitcnt vmcnt(0)"
          : "=&v"(z0), "=&v"(z1), "=&v"(z2), "=&v"(z3)
          : "v"(p0), "v"(p1), "v"(p2), "v"(p3)
          : "memory");
        if ((((z0 ^ expS) | (z1 ^ expS) | (z2 ^ expS) | (z3 ^ expS)) & SGN64) == 0ull)
          break;
        if (++rounds > 4096) { agentOnly = true; break; }   // safety escape
      }
      if (agentOnly) {
        // escape hatch: re-fetch from agent truth
        z0 = LD_REL(ZbA + sb + go0); z1 = LD_REL(ZbA + sb + go1);
        z2 = LD_REL(ZbA + sb + go2); z3 = LD_REL(ZbA + sb + go3);
        while ((((z0 ^ expS) | (z1 ^ expS) | (z2 ^ expS) | (z3 ^ expS)) & SGN64) != 0ull) {
          if ((z0 & SGN64) != expS) z0 = LD_REL(ZbA + sb + go0);
          if ((z1 & SGN64) != expS) z1 = LD_REL(ZbA + sb + go1);
          if ((z2 & SGN64) != expS) z2 = LD_REL(ZbA + sb + go2);
          if ((z3 & SGN64) != expS) z3 = LD_REL(ZbA + sb + go3);
        }
      }
    }

    // ---- stage raw z~ into LDS (strip signs) + per-thread per-col max ----
    uint_t m0 = 0u, m1 = 0u;
    {
      const ull_t u0 = z0 & MAG64, u1 = z1 & MAG64;
      const ull_t u2 = z2 & MAG64, u3 = z3 & MAG64;
      *(ull_t*)(zTf + tid * 4)               = u0;
      *(ull_t*)(zTf + 1024 + tid * 4)        = u1;
      *(ull_t*)(zTf + 2080 + tid * 4)        = u2;
      *(ull_t*)(zTf + 2080 + 1024 + tid * 4) = u3;
      uint_t t0 = pkmax16(pkmax16((uint_t)u0, (uint_t)(u0 >> 32)),
                          pkmax16((uint_t)u1, (uint_t)(u1 >> 32)));
      uint_t t1 = pkmax16(pkmax16((uint_t)u2, (uint_t)(u2 >> 32)),
                          pkmax16((uint_t)u3, (uint_t)(u3 >> 32)));
      m0 = umaxu(t0 & 0xFFFFu, t0 >> 16);
      m1 = umaxu(t1 & 0xFFFFu, t1 >> 16);
    }
    if (tid < 128) ipld[tid] = ipreg;
    uint_t pk = m0 | (m1 << 16);
    #pragma unroll
    for (int d = 1; d < 64; d <<= 1)
      pk = pkmax16(pk, (uint_t)__shfl_xor((int)pk, d));
    if (lane == 0) redm[wv] = pk;
    __syncthreads();                                   // B1

    // ---- hoisted epilogue inputs (registers; lets B2 be the last barrier) --
    float ipv[4];
    #pragma unroll
    for (int i = 0; i < 4; ++i)
      ipv[i] = ipld[(wv * 16 + quad * 4 + i) * 2 + (lrow & 1)];
    const uint_t rr = pkmax16(pkmax16(redm[0], redm[1]),
                              pkmax16(redm[2], redm[3]));
    const uint_t mm = (lrow & 1) ? (rr >> 16) : (rr & 0xFFFFu);
    const float lmax = __logf(b2f_u(mm << 16));  // identical across WGs of a col

    // ---- prefetch ip_rev[k+1] (overlaps MFMA) ----
    if (k < Ss - 1 && tid < 128) {
      const int v = ids[(c0 + myc) * Ss + (Ss - 2 - k)];
      ipreg = beta[(size_t)myr * Vv + v];
    }

    // ---- MFMA, K-split: this wave's 512-wide K-chunk of all 4 row-tiles ----
    f32x4 acc0 = {0.f, 0.f, 0.f, 0.f}, acc1 = acc0, acc2 = acc0, acc3 = acc0;
    #pragma unroll
    for (int kt = 0; kt < 16; ++kt) {
      short8 bfr = *(const short8*)(zbase + (wv * 16 + kt) * 32);
      acc0 = __builtin_amdgcn_mfma_f32_16x16x32_bf16(afr[kt],      bfr, acc0, 0, 0, 0);
      acc1 = __builtin_amdgcn_mfma_f32_16x16x32_bf16(afr[16 + kt], bfr, acc1, 0, 0, 0);
      acc2 = __builtin_amdgcn_mfma_f32_16x16x32_bf16(afr[32 + kt], bfr, acc2, 0, 0, 0);
      acc3 = __builtin_amdgcn_mfma_f32_16x16x32_bf16(afr[48 + kt], bfr, acc3, 0, 0, 0);
    }

    // ---- cross-wave K-reduction through LDS ----
    if (wv != 0) *(f32x4*)&red[0][wv][lane * 4] = acc0;
    if (wv != 1) *(f32x4*)&red[1][wv][lane * 4] = acc1;
    if (wv != 2) *(f32x4*)&red[2][wv][lane * 4] = acc2;
    if (wv != 3) *(f32x4*)&red[3][wv][lane * 4] = acc3;
    __syncthreads();                                   // B2 (last barrier)
    f32x4 sf = acc0;                                   // static own-tile select
    if (wv == 1) sf = acc1;
    else if (wv == 2) sf = acc2;
    else if (wv == 3) sf = acc3;
    #pragma unroll
    for (int v = 0; v < 4; ++v)
      if (v != wv) sf += *(const f32x4*)&red[wv][v][lane * 4];

    // ---- epilogue: y = log(sum) + mhat_{k-1} + ip; dual-publish z~^k ----
    const int  c   = lrow;                 // batch col (act lanes only)
    const int  rb  = wl * 64 + wv * 16 + quad * 4;   // output rows rb..rb+3
    const bool act = (lrow < 2);
    const float mnew = mprev + lmax;       // mhat_k
    if (act) {
      float yv4[4];
      #pragma unroll
      for (int i = 0; i < 4; ++i)
        yv4[i] = __logf(sf[i]) + mprev + ipv[i];
      uint_t o0 = (uint_t)f2b(__expf(yv4[0] - mnew)) |
                  ((uint_t)f2b(__expf(yv4[1] - mnew)) << 16);
      uint_t o1 = (uint_t)f2b(__expf(yv4[2] - mnew)) |
                  ((uint_t)f2b(__expf(yv4[3] - mnew)) << 16);
      const int   physW = (3 - (k % 3)) % 3;
      const ull_t orS   = (k & 1) ? SGN64 : 0ull;
      const ull_t val   = ((ull_t)o0 | ((ull_t)o1 << 32)) | orS;
      const size_t off  = (size_t)physW * 8192 + (size_t)(c0 + c) * 512 + (rb >> 2);
      *(volatile ull_t*)(ZbF + off) = val;   // fast: local XCD L2
      ST_REL(ZbA + off, val);                // agent: MALL (always, for mixed paths)
      // off critical path: ys[k]
      #pragma unroll
      for (int i = 0; i < 4; ++i)
        out[(size_t)k * (Hh * Bb) + (size_t)(rb + i) * Bb + (c0 + c)] = yv4[i];
      if (k == Ss - 1) {
        float4 yo; yo.x = yv4[0]; yo.y = yv4[1]; yo.z = yv4[2]; yo.w = yv4[3];
        *(float4*)(Y255 + (size_t)(c0 + c) * Hh + rb) = yo;
      }
    }
    mprev = mnew;
    // no loop-end barrier: B2 separates this step's LDS readers from the
    // next step's stage writes (zTf/ipld/redm written pre-B1(k+1) are only
    // read post-B1; red written post-B1(k+1) vs read pre-B1(k+1) arrival).
  }
}

// ---------------------------------------------------------------------------
// final[b] = log(sum_h e^{(g[h]-gm)+(y[h]-ym)}) - log(sum_h e^{g[h]-gm}) + ym
// ---------------------------------------------------------------------------
__global__ __launch_bounds__(256) void final_k(
    const float* __restrict__ gamma, const float* __restrict__ Y255,
    float* __restrict__ out)
{
  const int b = blockIdx.x;
  const int tid = threadIdx.x;
  __shared__ float sb[256];

  float ym = -3.0e38f;
  for (int h = tid; h < Hh; h += 256) ym = fmaxf(ym, Y255[(size_t)b * Hh + h]);
  sb[tid] = ym; __syncthreads();
  for (int off = 128; off; off >>= 1) {
    if (tid < off) sb[tid] = fmaxf(sb[tid], sb[tid + off]);
    __syncthreads();
  }
  ym = sb[0]; __syncthreads();

  float gm = -3.0e38f;
  for (int h = tid; h < Hh; h += 256) gm = fmaxf(gm, gamma[h]);
  sb[tid] = gm; __syncthreads();
  for (int off = 128; off; off >>= 1) {
    if (tid < off) sb[tid] = fmaxf(sb[tid], sb[tid + off]);
    __syncthreads();
  }
  gm = sb[0]; __syncthreads();

  float s1 = 0.f, s2 = 0.f;
  for (int h = tid; h < Hh; h += 256) {
    float gv = gamma[h] - gm;
    s1 += __expf(gv);
    s2 += __expf(gv + Y255[(size_t)b * Hh + h] - ym);
  }
  sb[tid] = s1; __syncthreads();
  for (int off = 128; off; off >>= 1) {
    if (tid < off) sb[tid] += sb[tid + off];
    __syncthreads();
  }
  s1 = sb[0]; __syncthreads();
  sb[tid] = s2; __syncthreads();
  for (int off = 128; off; off >>= 1) {
    if (tid < off) sb[tid] += sb[tid + off];
    __syncthreads();
  }
  s2 = sb[0];

  if (tid == 0)
    out[(size_t)Ss * Hh * Bb + b] = __logf(s2) - __logf(s1) + ym;
}

// ---------------------------------------------------------------------------
extern "C" void kernel_launch(void* const* d_in, const int* in_sizes, int n_in,
                              void* d_out, int out_size, void* d_ws, size_t ws_size,
                              hipStream_t stream) {
  (void)in_sizes; (void)n_in; (void)out_size;
  const int*   ids   = (const int*)d_in[0];
  const float* alpha = (const float*)d_in[1];
  const float* beta  = (const float*)d_in[2];
  const float* gamma = (const float*)d_in[3];
  float* out = (float*)d_out;
  char* ws = (char*)d_ws;

  if (ws_size < WS_NEED) return;   // clean fail rather than OOB

  ushort_t* Zbuf  = (ushort_t*)(ws + Z_OFF);
  ushort_t* ZbufF = (ushort_t*)(ws + ZF_OFF);
  float*    Y255  = (float*)(ws + Y_OFF);

  // AGENT-buffer epoch init: slots 0,1 -> sign=1 (0x80), slot 2 -> sign=0.
  // (Fast buffer is scrubbed in-kernel so the scrub lands in the L2 that
  //  consumers actually read.)
  hipMemsetAsync(ws + Z_OFF, 0x80, 2 * Z_SLOT, stream);
  hipMemsetAsync(ws + Z_OFF + 2 * Z_SLOT, 0x00, Z_SLOT, stream);

  {
    const float* a_alpha = alpha;
    const float* a_beta  = beta;
    const int*   a_ids   = ids;
    ushort_t* a_z = Zbuf;  ushort_t* a_zf = ZbufF;
    float* a_y = Y255;     float* a_out = out;
    void* args[] = {(void*)&a_alpha, (void*)&a_beta, (void*)&a_ids,
                    (void*)&a_z, (void*)&a_zf, (void*)&a_y, (void*)&a_out};
    hipError_t e = hipLaunchCooperativeKernel((const void*)hmm_persist,
                                              dim3(256), dim3(256), args, 0, stream);
    if (e != hipSuccess) {
      hipLaunchKernelGGL(hmm_persist, dim3(256), dim3(256), 0, stream,
                         alpha, beta, ids, Zbuf, ZbufF, Y255, out);
    }
  }

  hipLaunchKernelGGL(final_k, dim3(Bb), dim3(256), 0, stream, gamma, Y255, out);
}

// Round 4
// 1761.039 us; speedup vs baseline: 8.0693x; 8.0693x over previous
//
#include <hip/hip_runtime.h>
#include <cstdint>
#include <cstddef>

// Problem constants
#define Hh 2048
#define Vv 32000
#define Bb 16
#define Ss 256

typedef unsigned short ushort_t;
typedef unsigned int   uint_t;
typedef unsigned long long ull_t;

typedef __attribute__((ext_vector_type(8))) short short8;   // 8 x bf16 (4 VGPRs)
typedef __attribute__((ext_vector_type(4))) float f32x4;    // MFMA accumulator

// ---- workspace layout (bytes) ----
// Zbuf : 3 physical slots x [b16][h2048] bf16 z~ = exp(y - mhat), epoch parity
//        in the SIGN BITS (values >= 0, sign bit free). Slot = 64 KiB.
#define Z_SLOT   ((size_t)Bb * Hh * 2)          // 64 KiB per slot
#define WS_NEED  ((size_t)3 * Z_SLOT)

// Protocol (verified rounds 0-1): the DATA is the flag; AGENT scope only.
// (Round 3 proved the per-XCD-L2 "fast path" is unsound: non-coherent L2s
//  serve stale lines to sc0 polls indefinitely. All polling goes to MALL.)
//  - step k publishes z~^k to slot phys(k%3)=(3-k%3)%3, all bf16 sign bits
//    = k&1 (fire-and-forget 8B agent-scope stores).
//  - step k consumer spins on slot phys((k-1)%3) until sign bits ==(k-1)&1.
//    Stale slot data is exactly 3 steps old -> opposite parity; >=6-step
//    skew impossible (every WG consumes every group-WG's chunk each step).
//  - host memset: slots 0,1 -> 0x80 (parity1), slot 2 -> 0x00 (parity0);
//    each slot's first expected parity differs from its scrub pattern.
//  - lagged global max: mhat_k = mhat_{k-1} + log(max_h z~^{k-1}[c,h]),
//    derived bit-identically by every WG from the staged bf16 data (max is
//    order-independent). alpha rows sum to 1, ip<=0 => z~ <= 1.
#define LD_REL(p)     __hip_atomic_load((p), __ATOMIC_RELAXED, __HIP_MEMORY_SCOPE_AGENT)
#define ST_REL(p, v)  __hip_atomic_store((p), (v), __ATOMIC_RELAXED, __HIP_MEMORY_SCOPE_AGENT)

#define SGN64 0x8000800080008000ull
#define MAG64 0x7FFF7FFF7FFF7FFFull

__device__ __forceinline__ float b2f_u(uint_t u) {
  union { uint_t u; float f; } x; x.u = u; return x.f;
}
__device__ __forceinline__ ushort_t f2b(float f) {
  union { float f; uint_t u; } x; x.f = f;
  uint_t u = x.u;
  return (ushort_t)((u + 0x7FFFu + ((u >> 16) & 1u)) >> 16);   // RNE f32->bf16
}
__device__ __forceinline__ uint_t umaxu(uint_t a, uint_t b) { return a > b ? a : b; }
// packed 2 x u16 max (positive bf16 ordering == integer ordering)
__device__ __forceinline__ uint_t pkmax16(uint_t a, uint_t b) {
  uint_t lo = umaxu(a & 0xFFFFu, b & 0xFFFFu);
  uint_t hi = umaxu(a >> 16, b >> 16);
  return lo | (hi << 16);
}

// ---------------------------------------------------------------------------
// Persistent scan kernel. 256 WGs x 256 threads.
// 8 column-groups (g = blockIdx & 7) of 32 WGs. Group g owns batch columns
// {2g, 2g+1}. WG wl owns rows [wl*64, wl*64+64).
// K-SPLIT: wave wv owns K-chunk [wv*512, wv*512+512) of all 4 row-tiles;
// partials combined through LDS at barrier B2 (cuts per-WG LDS reads 4x and
// B2-syncs the 4 waves' publishes -> tighter group convoy).
// out[] writes are DEFERRED one step (register-carried) and issued right
// after B1, so no barrier's vmcnt(0) drain waits on their acks.
// After the scan, the 8 leader WGs (wl==0) compute final[b] directly from
// the published z~^255 (no separate kernel, no Y255 buffer):
//   final[b] = log(sum_h e^{gamma_h-gm} z~_h) - log(sum_h e^{gamma_h-gm}) + mhat_255
// ---------------------------------------------------------------------------
__global__ __launch_bounds__(256, 1) void hmm_persist(
    const float* __restrict__ alpha,
    const float* __restrict__ beta,
    const int*  __restrict__ ids,
    const float* __restrict__ gamma,
    ushort_t* __restrict__ Zbuf,
    float* __restrict__ out)
{
  const int w    = blockIdx.x;
  const int g    = w & 7;
  const int wl   = w >> 3;         // 0..31 within group -> row chunk
  const int c0   = g * 2;          // first batch column of group
  const int tid  = threadIdx.x;
  const int wv   = tid >> 6;       // wave 0..3 = K-chunk
  const int lane = tid & 63;
  const int lrow = lane & 15;
  const int quad = lane >> 4;

  __shared__ __align__(16) ushort_t zTf[2 * 2080];  // 2 cols x (2048+32 pad)
  __shared__ float ybuf[128];      // init only
  __shared__ float ipld[128];      // ip_rev[k]: [row][col], stride 2
  __shared__ uint_t redm[4];       // per-wave packed (c0max | c1max<<16)
  __shared__ __align__(16) float red[4][4][256];    // [tile][wave][lane*4]
  __shared__ float fred[4][4];     // finalizer reduction scratch
  __shared__ float mh2[2];         // finalizer: mhat_255 per col

  ull_t* ZbA = (ull_t*)Zbuf;

  // ---- preload alpha A-fragments: rows wl*64+t*16+lrow, K=wv*512+kt*32 ----
  short8 afr[64];                  // [t*16 + kt]
  #pragma unroll
  for (int t = 0; t < 4; ++t) {
    #pragma unroll
    for (int kt = 0; kt < 16; ++kt) {
      const float* arow = alpha + (size_t)(wl * 64 + t * 16 + lrow) * Hh
                          + wv * 512 + kt * 32 + quad * 8;
      float4 f0 = *(const float4*)arow;
      float4 f1 = *(const float4*)(arow + 4);
      short8 fr;
      fr[0] = (short)f2b(f0.x); fr[1] = (short)f2b(f0.y);
      fr[2] = (short)f2b(f0.z); fr[3] = (short)f2b(f0.w);
      fr[4] = (short)f2b(f1.x); fr[5] = (short)f2b(f1.y);
      fr[6] = (short)f2b(f1.z); fr[7] = (short)f2b(f1.w);
      afr[t * 16 + kt] = fr;
    }
  }

  const int myc = tid & 1;                 // gather mapping for tid<128
  const int myr = wl * 64 + (tid >> 1);
  float ipreg = 0.f;

  // ---- init (k=0): y^0 = beta[:, ids[:,S-1]]; publish z~^0=exp(y^0) ----
  {
    if (tid < 128) {
      const int v = ids[(c0 + myc) * Ss + (Ss - 1)];
      float yv = beta[(size_t)myr * Vv + v];
      ybuf[tid] = yv;
      out[(size_t)myr * Bb + (c0 + myc)] = yv;   // ys[0][h][b]
    }
    __syncthreads();
    if (tid < 32) {
      const int c = tid >> 4, q = tid & 15;
      uint_t b0 = f2b(__expf(ybuf[(q * 4 + 0) * 2 + c]));
      uint_t b1 = f2b(__expf(ybuf[(q * 4 + 1) * 2 + c]));
      uint_t b2 = f2b(__expf(ybuf[(q * 4 + 2) * 2 + c]));
      uint_t b3 = f2b(__expf(ybuf[(q * 4 + 3) * 2 + c]));
      ull_t val = (ull_t)(b0 | (b1 << 16)) | ((ull_t)(b2 | (b3 << 16)) << 32);
      ST_REL(ZbA + (size_t)(c0 + c) * 512 + (wl * 16 + q), val);  // slot0, par0
    }
    if (tid < 128) {   // prefetch ip_rev[1]
      const int v1 = ids[(c0 + myc) * Ss + (Ss - 2)];
      ipreg = beta[(size_t)myr * Vv + v1];
    }
  }

  // per-thread constant granule offsets
  const size_t go0 = (size_t)c0 * 512 + tid;
  const size_t go1 = (size_t)c0 * 512 + 256 + tid;
  const size_t go2 = (size_t)(c0 + 1) * 512 + tid;
  const size_t go3 = (size_t)(c0 + 1) * 512 + 256 + tid;

  float mprev = 0.f;               // mhat_{k-1} for col (lrow&1)
  const ushort_t* zbase = zTf + (lrow & 1) * 2080 + quad * 8;

  // epilogue geometry (thread-constant)
  const int  ec  = lrow;                           // batch col (act lanes)
  const int  rb  = wl * 64 + wv * 16 + quad * 4;   // output rows rb..rb+3
  const bool act = (lrow < 2);
  float pendy[4] = {0.f, 0.f, 0.f, 0.f};           // deferred out[] payload

  for (int k = 1; k < Ss; ++k) {
    const int   physR = (3 - ((k - 1) % 3)) % 3;
    const ull_t expS  = ((k - 1) & 1) ? SGN64 : 0ull;
    const size_t sb   = (size_t)physR * 8192;

    // ---- poll-is-the-load: spin on my 4 granules (agent scope / MALL) ----
    ull_t z0 = LD_REL(ZbA + sb + go0), z1 = LD_REL(ZbA + sb + go1);
    ull_t z2 = LD_REL(ZbA + sb + go2), z3 = LD_REL(ZbA + sb + go3);
    while ((((z0 ^ expS) | (z1 ^ expS) | (z2 ^ expS) | (z3 ^ expS)) & SGN64) != 0ull) {
      if ((z0 & SGN64) != expS) z0 = LD_REL(ZbA + sb + go0);
      if ((z1 & SGN64) != expS) z1 = LD_REL(ZbA + sb + go1);
      if ((z2 & SGN64) != expS) z2 = LD_REL(ZbA + sb + go2);
      if ((z3 & SGN64) != expS) z3 = LD_REL(ZbA + sb + go3);
    }

    // ---- stage raw z~ into LDS (strip signs) + per-thread per-col max ----
    uint_t m0, m1;
    {
      const ull_t u0 = z0 & MAG64, u1 = z1 & MAG64;
      const ull_t u2 = z2 & MAG64, u3 = z3 & MAG64;
      *(ull_t*)(zTf + tid * 4)               = u0;
      *(ull_t*)(zTf + 1024 + tid * 4)        = u1;
      *(ull_t*)(zTf + 2080 + tid * 4)        = u2;
      *(ull_t*)(zTf + 2080 + 1024 + tid * 4) = u3;
      uint_t t0 = pkmax16(pkmax16((uint_t)u0, (uint_t)(u0 >> 32)),
                          pkmax16((uint_t)u1, (uint_t)(u1 >> 32)));
      uint_t t1 = pkmax16(pkmax16((uint_t)u2, (uint_t)(u2 >> 32)),
                          pkmax16((uint_t)u3, (uint_t)(u3 >> 32)));
      m0 = umaxu(t0 & 0xFFFFu, t0 >> 16);
      m1 = umaxu(t1 & 0xFFFFu, t1 >> 16);
    }
    if (tid < 128) ipld[tid] = ipreg;
    uint_t pk = m0 | (m1 << 16);
    #pragma unroll
    for (int d = 1; d < 64; d <<= 1)
      pk = pkmax16(pk, (uint_t)__shfl_xor((int)pk, d));
    if (lane == 0) redm[wv] = pk;
    __syncthreads();                                   // B1

    // ---- deferred ys[k-1] writes: far from the next barrier's drain ----
    if (k > 1 && act) {
      #pragma unroll
      for (int i = 0; i < 4; ++i)
        out[(size_t)(k - 1) * (Hh * Bb) + (size_t)(rb + i) * Bb + (c0 + ec)] = pendy[i];
    }

    // ---- hoisted epilogue inputs (registers; B2 stays the last barrier) --
    float ipv[4];
    #pragma unroll
    for (int i = 0; i < 4; ++i)
      ipv[i] = ipld[(wv * 16 + quad * 4 + i) * 2 + (lrow & 1)];
    const uint_t rr = pkmax16(pkmax16(redm[0], redm[1]),
                              pkmax16(redm[2], redm[3]));
    const uint_t mm = (lrow & 1) ? (rr >> 16) : (rr & 0xFFFFu);
    const float lmax = __logf(b2f_u(mm << 16));  // identical across WGs of a col

    // ---- prefetch ip_rev[k+1] (overlaps MFMA) ----
    if (k < Ss - 1 && tid < 128) {
      const int v = ids[(c0 + myc) * Ss + (Ss - 2 - k)];
      ipreg = beta[(size_t)myr * Vv + v];
    }

    // ---- MFMA, K-split: this wave's 512-wide K-chunk of all 4 row-tiles ----
    f32x4 acc0 = {0.f, 0.f, 0.f, 0.f}, acc1 = acc0, acc2 = acc0, acc3 = acc0;
    #pragma unroll
    for (int kt = 0; kt < 16; ++kt) {
      short8 bfr = *(const short8*)(zbase + (wv * 16 + kt) * 32);
      acc0 = __builtin_amdgcn_mfma_f32_16x16x32_bf16(afr[kt],      bfr, acc0, 0, 0, 0);
      acc1 = __builtin_amdgcn_mfma_f32_16x16x32_bf16(afr[16 + kt], bfr, acc1, 0, 0, 0);
      acc2 = __builtin_amdgcn_mfma_f32_16x16x32_bf16(afr[32 + kt], bfr, acc2, 0, 0, 0);
      acc3 = __builtin_amdgcn_mfma_f32_16x16x32_bf16(afr[48 + kt], bfr, acc3, 0, 0, 0);
    }

    // ---- cross-wave K-reduction through LDS ----
    if (wv != 0) *(f32x4*)&red[0][wv][lane * 4] = acc0;
    if (wv != 1) *(f32x4*)&red[1][wv][lane * 4] = acc1;
    if (wv != 2) *(f32x4*)&red[2][wv][lane * 4] = acc2;
    if (wv != 3) *(f32x4*)&red[3][wv][lane * 4] = acc3;
    __syncthreads();                                   // B2 (last barrier)
    f32x4 sf = acc0;                                   // static own-tile select
    if (wv == 1) sf = acc1;
    else if (wv == 2) sf = acc2;
    else if (wv == 3) sf = acc3;
    #pragma unroll
    for (int v = 0; v < 4; ++v)
      if (v != wv) sf += *(const f32x4*)&red[wv][v][lane * 4];

    // ---- epilogue: y = log(sum) + mhat_{k-1} + ip; publish z~^k NOW ----
    const float mnew = mprev + lmax;       // mhat_k
    if (act) {
      #pragma unroll
      for (int i = 0; i < 4; ++i)
        pendy[i] = __logf(sf[i]) + mprev + ipv[i];
      uint_t o0 = (uint_t)f2b(__expf(pendy[0] - mnew)) |
                  ((uint_t)f2b(__expf(pendy[1] - mnew)) << 16);
      uint_t o1 = (uint_t)f2b(__expf(pendy[2] - mnew)) |
                  ((uint_t)f2b(__expf(pendy[3] - mnew)) << 16);
      const int   physW = (3 - (k % 3)) % 3;
      const ull_t orS   = (k & 1) ? SGN64 : 0ull;
      ST_REL(ZbA + (size_t)physW * 8192 + (size_t)(c0 + ec) * 512 + (rb >> 2),
             ((ull_t)o0 | ((ull_t)o1 << 32)) | orS);
    }
    mprev = mnew;
    // no loop-end barrier: B2 orders this step's LDS reads before the next
    // step's stage writes (all zTf/ipld/redm readers finish pre-B2; red
    // readers finish before they can arrive at B1(k+1)).
  }

  // ---- flush last deferred ys[255] ----
  if (act) {
    #pragma unroll
    for (int i = 0; i < 4; ++i)
      out[(size_t)(Ss - 1) * (Hh * Bb) + (size_t)(rb + i) * Bb + (c0 + ec)] = pendy[i];
  }

  // ---- fused finalizer: leader WG of each group computes final[c0..c0+1] --
  // final[c] = log(sum_h e^{g_h-gm} z~255_{c,h}) - log(sum_h e^{g_h-gm}) + mhat255_c
  // z~^255 lives in slot phys(255%3)=0, parity 1 - already published above.
  if (wl == 0) {
    if (tid < 2) mh2[tid] = mprev;   // tid0: lrow0 -> col c0; tid1 -> c0+1
    __syncthreads();
    // gamma: thread handles h = 4*tid..+3 and 1024+4*tid..+3
    float4 ga = *(const float4*)(gamma + 4 * tid);
    float4 gb = *(const float4*)(gamma + 1024 + 4 * tid);
    float gmx = fmaxf(fmaxf(fmaxf(ga.x, ga.y), fmaxf(ga.z, ga.w)),
                      fmaxf(fmaxf(gb.x, gb.y), fmaxf(gb.z, gb.w)));
    #pragma unroll
    for (int d = 1; d < 64; d <<= 1) gmx = fmaxf(gmx, __shfl_xor(gmx, d));
    if (lane == 0) fred[wv][0] = gmx;
    __syncthreads();
    const float gm = fmaxf(fmaxf(fred[0][0], fred[1][0]),
                           fmaxf(fred[2][0], fred[3][0]));
    float wgt[8];
    wgt[0] = __expf(ga.x - gm); wgt[1] = __expf(ga.y - gm);
    wgt[2] = __expf(ga.z - gm); wgt[3] = __expf(ga.w - gm);
    wgt[4] = __expf(gb.x - gm); wgt[5] = __expf(gb.y - gm);
    wgt[6] = __expf(gb.z - gm); wgt[7] = __expf(gb.w - gm);
    float s1 = ((wgt[0] + wgt[1]) + (wgt[2] + wgt[3])) +
               ((wgt[4] + wgt[5]) + (wgt[6] + wgt[7]));
    // poll z~^255 (same granule mapping as the loop; data already published)
    ull_t z0 = LD_REL(ZbA + go0), z1 = LD_REL(ZbA + go1);
    ull_t z2 = LD_REL(ZbA + go2), z3 = LD_REL(ZbA + go3);
    while ((((z0 ^ SGN64) | (z1 ^ SGN64) | (z2 ^ SGN64) | (z3 ^ SGN64)) & SGN64) != 0ull) {
      if ((z0 & SGN64) != SGN64) z0 = LD_REL(ZbA + go0);
      if ((z1 & SGN64) != SGN64) z1 = LD_REL(ZbA + go1);
      if ((z2 & SGN64) != SGN64) z2 = LD_REL(ZbA + go2);
      if ((z3 & SGN64) != SGN64) z3 = LD_REL(ZbA + go3);
    }
    float s2a = 0.f, s2b = 0.f;
    #pragma unroll
    for (int i = 0; i < 4; ++i) {
      s2a += wgt[i]     * b2f_u(((uint_t)(z0 >> (16 * i)) & 0x7FFFu) << 16);
      s2a += wgt[4 + i] * b2f_u(((uint_t)(z1 >> (16 * i)) & 0x7FFFu) << 16);
      s2b += wgt[i]     * b2f_u(((uint_t)(z2 >> (16 * i)) & 0x7FFFu) << 16);
      s2b += wgt[4 + i] * b2f_u(((uint_t)(z3 >> (16 * i)) & 0x7FFFu) << 16);
    }
    #pragma unroll
    for (int d = 1; d < 64; d <<= 1) {
      s1  += __shfl_xor(s1, d);
      s2a += __shfl_xor(s2a, d);
      s2b += __shfl_xor(s2b, d);
    }
    if (lane == 0) { fred[wv][1] = s1; fred[wv][2] = s2a; fred[wv][3] = s2b; }
    __syncthreads();
    if (tid == 0) {
      float S1 = ((fred[0][1] + fred[1][1]) + (fred[2][1] + fred[3][1]));
      float Sa = ((fred[0][2] + fred[1][2]) + (fred[2][2] + fred[3][2]));
      float Sb = ((fred[0][3] + fred[1][3]) + (fred[2][3] + fred[3][3]));
      const float ls1 = __logf(S1);
      out[(size_t)Ss * Hh * Bb + c0]     = __logf(Sa) - ls1 + mh2[0];
      out[(size_t)Ss * Hh * Bb + c0 + 1] = __logf(Sb) - ls1 + mh2[1];
    }
  }
}

// ---------------------------------------------------------------------------
extern "C" void kernel_launch(void* const* d_in, const int* in_sizes, int n_in,
                              void* d_out, int out_size, void* d_ws, size_t ws_size,
                              hipStream_t stream) {
  (void)in_sizes; (void)n_in; (void)out_size;
  const int*   ids   = (const int*)d_in[0];
  const float* alpha = (const float*)d_in[1];
  const float* beta  = (const float*)d_in[2];
  const float* gamma = (const float*)d_in[3];
  float* out = (float*)d_out;
  char* ws = (char*)d_ws;

  if (ws_size < WS_NEED) return;   // clean fail rather than OOB

  ushort_t* Zbuf = (ushort_t*)ws;

  // Epoch-pattern init: slots 0,1 -> sign=1 (0x80), slot 2 -> sign=0.
  // Each slot's first poll expects the opposite parity, so consumers block
  // until real data lands; also scrubs the previous launch's leftovers.
  hipMemsetAsync(ws, 0x80, 2 * Z_SLOT, stream);
  hipMemsetAsync(ws + 2 * Z_SLOT, 0x00, Z_SLOT, stream);

  {
    const float* a_alpha = alpha;
    const float* a_beta  = beta;
    const int*   a_ids   = ids;
    const float* a_gamma = gamma;
    ushort_t* a_z = Zbuf;  float* a_out = out;
    void* args[] = {(void*)&a_alpha, (void*)&a_beta, (void*)&a_ids,
                    (void*)&a_gamma, (void*)&a_z, (void*)&a_out};
    hipError_t e = hipLaunchCooperativeKernel((const void*)hmm_persist,
                                              dim3(256), dim3(256), args, 0, stream);
    if (e != hipSuccess) {
      hipLaunchKernelGGL(hmm_persist, dim3(256), dim3(256), 0, stream,
                         alpha, beta, ids, gamma, Zbuf, out);
    }
  }
}

// Round 5
// 1725.701 us; speedup vs baseline: 8.2345x; 1.0205x over previous
//
#include <hip/hip_runtime.h>
#include <cstdint>
#include <cstddef>

// Problem constants
#define Hh 2048
#define Vv 32000
#define Bb 16
#define Ss 256

typedef unsigned short ushort_t;
typedef unsigned int   uint_t;
typedef unsigned long long ull_t;

typedef __attribute__((ext_vector_type(8))) short short8;   // 8 x bf16 (4 VGPRs)
typedef __attribute__((ext_vector_type(4))) float f32x4;    // MFMA accumulator

// ---- workspace layout (bytes) ----
// Zbuf : 3 physical slots x [b16][h2048] bf16 z~ = exp(y - mhat), epoch parity
//        in the SIGN BITS (values >= 0, sign bit free). Slot = 64 KiB.
#define Z_SLOT   ((size_t)Bb * Hh * 2)          // 64 KiB per slot
#define WS_NEED  ((size_t)3 * Z_SLOT)

// Protocol (verified rounds 0/1/4): the DATA is the flag; AGENT scope only.
//  - step k publishes z~^k to slot phys(k%3)=(3-k%3)%3, all bf16 sign bits
//    = k&1 (fire-and-forget 8B agent-scope stores).
//  - step k consumer spins on slot phys((k-1)%3) until sign bits ==(k-1)&1.
//    Stale slot data is exactly 3 steps old -> opposite parity; >=6-step
//    skew impossible (every WG consumes every group-WG's rows each step).
//  - host memset: slots 0,1 -> 0x80 (parity1), slot 2 -> 0x00 (parity0).
//  - lagged global max: mhat_k = mhat_{k-1} + log(max_h z~^{k-1}[c,h]),
//    derived bit-identically by every WG from the same bf16 data (per-wave
//    partials combined in fixed order). alpha rows sum to 1, ip<=0 => z~<=1.
// NEW this round (geometry only, protocol untouched):
//  - wave wv polls/stages ONLY its K-chunk rows [wv*512,(wv+1)*512): each
//    thread depends on exactly 2 producer WGs -> narrow tail.
//  - ONE barrier per step (B2). zTf zones are wave-local (lgkmcnt-ordered
//    within the wave); red/redm/ipld double-buffered by k&1 so the single
//    barrier separates generations.
//  - publish is the FIRST store after B2 (R4 lesson: nothing ack-heavy
//    between compute-done and publish; out[] writes go after publish and
//    have a full step to ack before the next B2 drain).
#define LD_REL(p)     __hip_atomic_load((p), __ATOMIC_RELAXED, __HIP_MEMORY_SCOPE_AGENT)
#define ST_REL(p, v)  __hip_atomic_store((p), (v), __ATOMIC_RELAXED, __HIP_MEMORY_SCOPE_AGENT)

#define SGN64 0x8000800080008000ull
#define MAG64 0x7FFF7FFF7FFF7FFFull

__device__ __forceinline__ float b2f_u(uint_t u) {
  union { uint_t u; float f; } x; x.u = u; return x.f;
}
__device__ __forceinline__ ushort_t f2b(float f) {
  union { float f; uint_t u; } x; x.f = f;
  uint_t u = x.u;
  return (ushort_t)((u + 0x7FFFu + ((u >> 16) & 1u)) >> 16);   // RNE f32->bf16
}
__device__ __forceinline__ uint_t umaxu(uint_t a, uint_t b) { return a > b ? a : b; }
// packed 2 x u16 max (positive bf16 ordering == integer ordering)
__device__ __forceinline__ uint_t pkmax16(uint_t a, uint_t b) {
  uint_t lo = umaxu(a & 0xFFFFu, b & 0xFFFFu);
  uint_t hi = umaxu(a >> 16, b >> 16);
  return lo | (hi << 16);
}

// ---------------------------------------------------------------------------
// Persistent scan kernel. 256 WGs x 256 threads.
// 8 column-groups (g = blockIdx & 7) of 32 WGs. Group g owns batch columns
// {2g, 2g+1}. WG wl owns rows [wl*64, wl*64+64).
// K-SPLIT: wave wv owns K-chunk [wv*512, wv*512+512) of all 4 row-tiles;
// partials combined through LDS at the single barrier B2.
// ---------------------------------------------------------------------------
__global__ __launch_bounds__(256, 1) void hmm_persist(
    const float* __restrict__ alpha,
    const float* __restrict__ beta,
    const int*  __restrict__ ids,
    const float* __restrict__ gamma,
    ushort_t* __restrict__ Zbuf,
    float* __restrict__ out)
{
  const int w    = blockIdx.x;
  const int g    = w & 7;
  const int wl   = w >> 3;         // 0..31 within group -> row chunk
  const int c0   = g * 2;          // first batch column of group
  const int tid  = threadIdx.x;
  const int wv   = tid >> 6;       // wave 0..3 = K-chunk
  const int lane = tid & 63;
  const int lrow = lane & 15;
  const int quad = lane >> 4;

  __shared__ __align__(16) ushort_t zTf[2 * 2080];  // 2 cols x (2048+32 pad)
  __shared__ float ybuf[128];      // init only
  __shared__ float ipld[2][128];   // ip_rev[k]: [buf][row*2+col]
  __shared__ uint_t redm[2][4];    // [buf][wave] packed (c0max | c1max<<16)
  __shared__ __align__(16) float red[2][4][4][256]; // [buf][tile][wave][lane*4]
  __shared__ float fred[4][4];     // finalizer reduction scratch
  __shared__ float mh2[2];         // finalizer: mhat_255 per col

  ull_t* ZbA = (ull_t*)Zbuf;

  // ---- preload alpha A-fragments: rows wl*64+t*16+lrow, K=wv*512+kt*32 ----
  short8 afr[64];                  // [t*16 + kt]
  #pragma unroll
  for (int t = 0; t < 4; ++t) {
    #pragma unroll
    for (int kt = 0; kt < 16; ++kt) {
      const float* arow = alpha + (size_t)(wl * 64 + t * 16 + lrow) * Hh
                          + wv * 512 + kt * 32 + quad * 8;
      float4 f0 = *(const float4*)arow;
      float4 f1 = *(const float4*)(arow + 4);
      short8 fr;
      fr[0] = (short)f2b(f0.x); fr[1] = (short)f2b(f0.y);
      fr[2] = (short)f2b(f0.z); fr[3] = (short)f2b(f0.w);
      fr[4] = (short)f2b(f1.x); fr[5] = (short)f2b(f1.y);
      fr[6] = (short)f2b(f1.z); fr[7] = (short)f2b(f1.w);
      afr[t * 16 + kt] = fr;
    }
  }

  const int myc = tid & 1;                 // ip gather mapping for tid<128
  const int myr = wl * 64 + (tid >> 1);
  float ipreg = 0.f;

  // ---- init (k=0): y^0 = beta[:, ids[:,S-1]]; publish z~^0=exp(y^0) ----
  {
    if (tid < 128) {
      const int v = ids[(c0 + myc) * Ss + (Ss - 1)];
      float yv = beta[(size_t)myr * Vv + v];
      ybuf[tid] = yv;
      out[(size_t)myr * Bb + (c0 + myc)] = yv;   // ys[0][h][b]
    }
    __syncthreads();
    if (tid < 32) {
      const int c = tid >> 4, q = tid & 15;
      uint_t b0 = f2b(__expf(ybuf[(q * 4 + 0) * 2 + c]));
      uint_t b1 = f2b(__expf(ybuf[(q * 4 + 1) * 2 + c]));
      uint_t b2 = f2b(__expf(ybuf[(q * 4 + 2) * 2 + c]));
      uint_t b3 = f2b(__expf(ybuf[(q * 4 + 3) * 2 + c]));
      ull_t val = (ull_t)(b0 | (b1 << 16)) | ((ull_t)(b2 | (b3 << 16)) << 32);
      ST_REL(ZbA + (size_t)(c0 + c) * 512 + (wl * 16 + q), val);  // slot0, par0
    }
    if (tid < 128) {   // prefetch ip_rev[1]
      const int v1 = ids[(c0 + myc) * Ss + (Ss - 2)];
      ipreg = beta[(size_t)myr * Vv + v1];
    }
    __syncthreads();   // ybuf done before anything else reuses LDS region
  }

  // per-thread granule offsets: wave-chunk mapping (2 producer WGs/thread)
  const int h4a = wv * 128 + lane;
  const int h4b = h4a + 64;
  const size_t go0 = (size_t)c0 * 512 + h4a;
  const size_t go1 = (size_t)c0 * 512 + h4b;
  const size_t go2 = (size_t)(c0 + 1) * 512 + h4a;
  const size_t go3 = (size_t)(c0 + 1) * 512 + h4b;

  float mprev = 0.f;               // mhat_{k-1} for col (lrow&1)
  const ushort_t* zbase = zTf + (lrow & 1) * 2080 + quad * 8;

  // epilogue geometry (thread-constant)
  const int  ec  = lrow;                           // batch col (act lanes)
  const int  rb  = wl * 64 + wv * 16 + quad * 4;   // output rows rb..rb+3
  const bool act = (lrow < 2);
  float pendy[4] = {0.f, 0.f, 0.f, 0.f};           // deferred out[] payload

  for (int k = 1; k < Ss; ++k) {
    const int   pb    = k & 1;     // LDS generation buffer
    const int   physR = (3 - ((k - 1) % 3)) % 3;
    const ull_t expS  = ((k - 1) & 1) ? SGN64 : 0ull;
    const size_t sb   = (size_t)physR * 8192;

    // ---- per-wave poll-is-the-load on own K-chunk granules ----
    ull_t z0 = LD_REL(ZbA + sb + go0), z1 = LD_REL(ZbA + sb + go1);
    ull_t z2 = LD_REL(ZbA + sb + go2), z3 = LD_REL(ZbA + sb + go3);
    while ((((z0 ^ expS) | (z1 ^ expS) | (z2 ^ expS) | (z3 ^ expS)) & SGN64) != 0ull) {
      if ((z0 & SGN64) != expS) z0 = LD_REL(ZbA + sb + go0);
      if ((z1 & SGN64) != expS) z1 = LD_REL(ZbA + sb + go1);
      if ((z2 & SGN64) != expS) z2 = LD_REL(ZbA + sb + go2);
      if ((z3 & SGN64) != expS) z3 = LD_REL(ZbA + sb + go3);
    }

    // ---- stage into own wave-local zTf zone + per-col partial max ----
    uint_t m0, m1;
    {
      const ull_t u0 = z0 & MAG64, u1 = z1 & MAG64;
      const ull_t u2 = z2 & MAG64, u3 = z3 & MAG64;
      *(ull_t*)(zTf + 4 * h4a)        = u0;
      *(ull_t*)(zTf + 4 * h4b)        = u1;
      *(ull_t*)(zTf + 2080 + 4 * h4a) = u2;
      *(ull_t*)(zTf + 2080 + 4 * h4b) = u3;
      uint_t t0 = pkmax16(pkmax16((uint_t)u0, (uint_t)(u0 >> 32)),
                          pkmax16((uint_t)u1, (uint_t)(u1 >> 32)));
      uint_t t1 = pkmax16(pkmax16((uint_t)u2, (uint_t)(u2 >> 32)),
                          pkmax16((uint_t)u3, (uint_t)(u3 >> 32)));
      m0 = umaxu(t0 & 0xFFFFu, t0 >> 16);
      m1 = umaxu(t1 & 0xFFFFu, t1 >> 16);
    }
    if (tid < 128) ipld[pb][tid] = ipreg;
    uint_t pk = m0 | (m1 << 16);   // partial over rows [wv*512,(wv+1)*512)
    #pragma unroll
    for (int d = 1; d < 64; d <<= 1)
      pk = pkmax16(pk, (uint_t)__shfl_xor((int)pk, d));
    if (lane == 0) redm[pb][wv] = pk;

    // wave-local write->read ordering for zTf (no barrier here!)
    asm volatile("s_waitcnt lgkmcnt(0)" ::: "memory");
    __builtin_amdgcn_sched_barrier(0);

    // ---- prefetch ip_rev[k+1] (overlaps MFMA) ----
    if (k < Ss - 1 && tid < 128) {
      const int v = ids[(c0 + myc) * Ss + (Ss - 2 - k)];
      ipreg = beta[(size_t)myr * Vv + v];
    }

    // ---- MFMA, K-split: this wave's 512-wide K-chunk of all 4 row-tiles ----
    f32x4 acc0 = {0.f, 0.f, 0.f, 0.f}, acc1 = acc0, acc2 = acc0, acc3 = acc0;
    #pragma unroll
    for (int kt = 0; kt < 16; ++kt) {
      short8 bfr = *(const short8*)(zbase + (wv * 16 + kt) * 32);
      acc0 = __builtin_amdgcn_mfma_f32_16x16x32_bf16(afr[kt],      bfr, acc0, 0, 0, 0);
      acc1 = __builtin_amdgcn_mfma_f32_16x16x32_bf16(afr[16 + kt], bfr, acc1, 0, 0, 0);
      acc2 = __builtin_amdgcn_mfma_f32_16x16x32_bf16(afr[32 + kt], bfr, acc2, 0, 0, 0);
      acc3 = __builtin_amdgcn_mfma_f32_16x16x32_bf16(afr[48 + kt], bfr, acc3, 0, 0, 0);
    }

    // ---- cross-wave K-reduction through LDS (double-buffered) ----
    if (wv != 0) *(f32x4*)&red[pb][0][wv][lane * 4] = acc0;
    if (wv != 1) *(f32x4*)&red[pb][1][wv][lane * 4] = acc1;
    if (wv != 2) *(f32x4*)&red[pb][2][wv][lane * 4] = acc2;
    if (wv != 3) *(f32x4*)&red[pb][3][wv][lane * 4] = acc3;
    __syncthreads();                                   // B2 — the ONLY barrier
    f32x4 sf = acc0;                                   // static own-tile select
    if (wv == 1) sf = acc1;
    else if (wv == 2) sf = acc2;
    else if (wv == 3) sf = acc3;
    #pragma unroll
    for (int v = 0; v < 4; ++v)
      if (v != wv) sf += *(const f32x4*)&red[pb][wv][v][lane * 4];

    // ---- combine col max (fixed order -> bit-identical across WGs) ----
    const uint_t rr = pkmax16(pkmax16(redm[pb][0], redm[pb][1]),
                              pkmax16(redm[pb][2], redm[pb][3]));
    const uint_t mm = (lrow & 1) ? (rr >> 16) : (rr & 0xFFFFu);
    const float lmax = __logf(b2f_u(mm << 16));
    float ipv[4];
    #pragma unroll
    for (int i = 0; i < 4; ++i)
      ipv[i] = ipld[pb][(wv * 16 + quad * 4 + i) * 2 + (lrow & 1)];

    // ---- epilogue: y = log(sum) + mhat_{k-1} + ip; publish FIRST ----
    const float mnew = mprev + lmax;       // mhat_k
    if (act) {
      float yv4[4];
      #pragma unroll
      for (int i = 0; i < 4; ++i)
        yv4[i] = __logf(sf[i]) + mprev + ipv[i];
      uint_t o0 = (uint_t)f2b(__expf(yv4[0] - mnew)) |
                  ((uint_t)f2b(__expf(yv4[1] - mnew)) << 16);
      uint_t o1 = (uint_t)f2b(__expf(yv4[2] - mnew)) |
                  ((uint_t)f2b(__expf(yv4[3] - mnew)) << 16);
      const int   physW = (3 - (k % 3)) % 3;
      const ull_t orS   = (k & 1) ? SGN64 : 0ull;
      ST_REL(ZbA + (size_t)physW * 8192 + (size_t)(c0 + ec) * 512 + (rb >> 2),
             ((ull_t)o0 | ((ull_t)o1 << 32)) | orS);
      // deferred ys[k-1] AFTER publish: a full step (~10K cy) to ack
      #pragma unroll
      for (int i = 0; i < 4; ++i)
        out[(size_t)(k - 1) * (Hh * Bb) + (size_t)(rb + i) * Bb + (c0 + ec)] = pendy[i];
      #pragma unroll
      for (int i = 0; i < 4; ++i) pendy[i] = yv4[i];
    }
    mprev = mnew;
    // no second barrier: zTf zones are wave-local; red/redm/ipld generation
    // pb is read post-B2(k) and next written pre-B2(k+2), with B2(k+1)
    // separating readers from writers.
  }

  // ---- flush last deferred ys[255] ----
  if (act) {
    #pragma unroll
    for (int i = 0; i < 4; ++i)
      out[(size_t)(Ss - 1) * (Hh * Bb) + (size_t)(rb + i) * Bb + (c0 + ec)] = pendy[i];
  }

  // ---- fused finalizer: leader WG of each group computes final[c0..c0+1] --
  // final[c] = log(sum_h e^{g_h-gm} z~255_{c,h}) - log(sum_h e^{g_h-gm}) + mhat255_c
  // z~^255 lives in slot phys(255%3)=0, parity 1 — published above.
  if (wl == 0) {
    if (tid < 2) mh2[tid] = mprev;   // tid0: lrow0 -> col c0; tid1 -> c0+1
    __syncthreads();
    // gamma rows matching this thread's granules:
    //   z0/z2 -> rows wv*512 + 4*lane .. +3 ; z1/z3 -> rows wv*512+256+4*lane
    float4 ga = *(const float4*)(gamma + wv * 512 + 4 * lane);
    float4 gb = *(const float4*)(gamma + wv * 512 + 256 + 4 * lane);
    float gmx = fmaxf(fmaxf(fmaxf(ga.x, ga.y), fmaxf(ga.z, ga.w)),
                      fmaxf(fmaxf(gb.x, gb.y), fmaxf(gb.z, gb.w)));
    #pragma unroll
    for (int d = 1; d < 64; d <<= 1) gmx = fmaxf(gmx, __shfl_xor(gmx, d));
    if (lane == 0) fred[wv][0] = gmx;
    __syncthreads();
    const float gm = fmaxf(fmaxf(fred[0][0], fred[1][0]),
                           fmaxf(fred[2][0], fred[3][0]));
    float wga[4], wgb[4];
    wga[0] = __expf(ga.x - gm); wga[1] = __expf(ga.y - gm);
    wga[2] = __expf(ga.z - gm); wga[3] = __expf(ga.w - gm);
    wgb[0] = __expf(gb.x - gm); wgb[1] = __expf(gb.y - gm);
    wgb[2] = __expf(gb.z - gm); wgb[3] = __expf(gb.w - gm);
    float s1 = ((wga[0] + wga[1]) + (wga[2] + wga[3])) +
               ((wgb[0] + wgb[1]) + (wgb[2] + wgb[3]));
    // poll z~^255 (same wave-chunk granule mapping as the loop)
    ull_t z0 = LD_REL(ZbA + go0), z1 = LD_REL(ZbA + go1);
    ull_t z2 = LD_REL(ZbA + go2), z3 = LD_REL(ZbA + go3);
    while ((((z0 ^ SGN64) | (z1 ^ SGN64) | (z2 ^ SGN64) | (z3 ^ SGN64)) & SGN64) != 0ull) {
      if ((z0 & SGN64) != SGN64) z0 = LD_REL(ZbA + go0);
      if ((z1 & SGN64) != SGN64) z1 = LD_REL(ZbA + go1);
      if ((z2 & SGN64) != SGN64) z2 = LD_REL(ZbA + go2);
      if ((z3 & SGN64) != SGN64) z3 = LD_REL(ZbA + go3);
    }
    float s2a = 0.f, s2b = 0.f;
    #pragma unroll
    for (int i = 0; i < 4; ++i) {
      s2a += wga[i] * b2f_u(((uint_t)(z0 >> (16 * i)) & 0x7FFFu) << 16);
      s2a += wgb[i] * b2f_u(((uint_t)(z1 >> (16 * i)) & 0x7FFFu) << 16);
      s2b += wga[i] * b2f_u(((uint_t)(z2 >> (16 * i)) & 0x7FFFu) << 16);
      s2b += wgb[i] * b2f_u(((uint_t)(z3 >> (16 * i)) & 0x7FFFu) << 16);
    }
    #pragma unroll
    for (int d = 1; d < 64; d <<= 1) {
      s1  += __shfl_xor(s1, d);
      s2a += __shfl_xor(s2a, d);
      s2b += __shfl_xor(s2b, d);
    }
    if (lane == 0) { fred[wv][1] = s1; fred[wv][2] = s2a; fred[wv][3] = s2b; }
    __syncthreads();
    if (tid == 0) {
      float S1 = ((fred[0][1] + fred[1][1]) + (fred[2][1] + fred[3][1]));
      float Sa = ((fred[0][2] + fred[1][2]) + (fred[2][2] + fred[3][2]));
      float Sb = ((fred[0][3] + fred[1][3]) + (fred[2][3] + fred[3][3]));
      const float ls1 = __logf(S1);
      out[(size_t)Ss * Hh * Bb + c0]     = __logf(Sa) - ls1 + mh2[0];
      out[(size_t)Ss * Hh * Bb + c0 + 1] = __logf(Sb) - ls1 + mh2[1];
    }
  }
}

// ---------------------------------------------------------------------------
extern "C" void kernel_launch(void* const* d_in, const int* in_sizes, int n_in,
                              void* d_out, int out_size, void* d_ws, size_t ws_size,
                              hipStream_t stream) {
  (void)in_sizes; (void)n_in; (void)out_size;
  const int*   ids   = (const int*)d_in[0];
  const float* alpha = (const float*)d_in[1];
  const float* beta  = (const float*)d_in[2];
  const float* gamma = (const float*)d_in[3];
  float* out = (float*)d_out;
  char* ws = (char*)d_ws;

  if (ws_size < WS_NEED) return;   // clean fail rather than OOB

  ushort_t* Zbuf = (ushort_t*)ws;

  // Epoch-pattern init: slots 0,1 -> sign=1 (0x80), slot 2 -> sign=0.
  // Each slot's first poll expects the opposite parity, so consumers block
  // until real data lands; also scrubs the previous launch's leftovers.
  hipMemsetAsync(ws, 0x80, 2 * Z_SLOT, stream);
  hipMemsetAsync(ws + 2 * Z_SLOT, 0x00, Z_SLOT, stream);

  {
    const float* a_alpha = alpha;
    const float* a_beta  = beta;
    const int*   a_ids   = ids;
    const float* a_gamma = gamma;
    ushort_t* a_z = Zbuf;  float* a_out = out;
    void* args[] = {(void*)&a_alpha, (void*)&a_beta, (void*)&a_ids,
                    (void*)&a_gamma, (void*)&a_z, (void*)&a_out};
    hipError_t e = hipLaunchCooperativeKernel((const void*)hmm_persist,
                                              dim3(256), dim3(256), args, 0, stream);
    if (e != hipSuccess) {
      hipLaunchKernelGGL(hmm_persist, dim3(256), dim3(256), 0, stream,
                         alpha, beta, ids, gamma, Zbuf, out);
    }
  }
}

// Round 6
// 1473.100 us; speedup vs baseline: 9.6466x; 1.1715x over previous
//
#include <hip/hip_runtime.h>
#include <cstdint>
#include <cstddef>

// Problem constants
#define Hh 2048
#define Vv 32000
#define Bb 16
#define Ss 256

typedef unsigned short ushort_t;
typedef unsigned int   uint_t;
typedef unsigned long long ull_t;

typedef __attribute__((ext_vector_type(8))) short short8;   // 8 x bf16 (4 VGPRs)
typedef __attribute__((ext_vector_type(4))) float f32x4;    // MFMA accumulator
typedef __attribute__((ext_vector_type(2))) ull_t ullx2;    // 16B (4 VGPRs)

// ---- workspace layout (bytes) ----
// Zbuf : 3 physical slots x [b16][h2048] bf16 z~ = exp(y - mhat), epoch parity
//        in the SIGN BITS (values >= 0, sign bit free). Slot = 64 KiB.
#define Z_SLOT   ((size_t)Bb * Hh * 2)          // 64 KiB per slot
#define WS_NEED  ((size_t)3 * Z_SLOT)

// Protocol (verified rounds 0/1/4/5): the DATA is the flag; AGENT scope only.
//  - step k publishes z~^k to slot phys(k%3)=(3-k%3)%3, all bf16 sign bits
//    = k&1 (fire-and-forget 8B agent-scope stores).
//  - step k consumer spins on slot phys((k-1)%3) until sign bits ==(k-1)&1.
//    Stale slot data is exactly 3 steps old -> opposite parity; >=6-step
//    skew impossible (every WG consumes every group-WG's rows each step).
//  - host memset: slots 0,1 -> 0x80 (parity1), slot 2 -> 0x00 (parity0).
//  - lagged global max: mhat_k = mhat_{k-1} + log(max_h z~^{k-1}[c,h]),
//    derived bit-identically by every WG from the same bf16 data (per-wave
//    partials combined in fixed order). alpha rows sum to 1, ip<=0 => z~<=1.
// NEW this round (R6; consumption mechanics only, protocol untouched):
//  - POLL THROTTLE: escalating s_sleep between failed poll rounds. In steady
//    state every thread spends most of the step spinning sc1 loads into the
//    MALL (coherence point); the aggregate request stream inflates every
//    sc1 RTT (publish ack + discovery + fetch). Sleeping caps the chip-wide
//    poll rate ~5-10x at <=1024cy detection quantization.
//  - PAIRED 16B POLLS: thread polls granules (2*lane, 2*lane+1) per col with
//    ONE global_load_dwordx4 sc0 sc1 (system-scoped; served through the
//    memory-side MALL, so never staler than agent scope — R3's stale-L2
//    failure was sc0-only). Each 8B half carries its own 4 parity bits, so
//    a torn 16B read simply retries. Halves poll request count.
//  - beta/ids prefetch hoisted ABOVE the poll (address independent of z):
//    the ~900cy+ HBM gather completes under the poll wait instead of
//    leaking into B2's vmcnt(0) drain.
#define LD_REL(p)     __hip_atomic_load((p), __ATOMIC_RELAXED, __HIP_MEMORY_SCOPE_AGENT)
#define ST_REL(p, v)  __hip_atomic_store((p), (v), __ATOMIC_RELAXED, __HIP_MEMORY_SCOPE_AGENT)

#define SGN64 0x8000800080008000ull
#define MAG64 0x7FFF7FFF7FFF7FFFull

__device__ __forceinline__ float b2f_u(uint_t u) {
  union { uint_t u; float f; } x; x.u = u; return x.f;
}
__device__ __forceinline__ ushort_t f2b(float f) {
  union { float f; uint_t u; } x; x.f = f;
  uint_t u = x.u;
  return (ushort_t)((u + 0x7FFFu + ((u >> 16) & 1u)) >> 16);   // RNE f32->bf16
}
__device__ __forceinline__ uint_t umaxu(uint_t a, uint_t b) { return a > b ? a : b; }
// packed 2 x u16 max (positive bf16 ordering == integer ordering)
__device__ __forceinline__ uint_t pkmax16(uint_t a, uint_t b) {
  uint_t lo = umaxu(a & 0xFFFFu, b & 0xFFFFu);
  uint_t hi = umaxu(a >> 16, b >> 16);
  return lo | (hi << 16);
}

// ---------------------------------------------------------------------------
// Persistent scan kernel. 256 WGs x 256 threads.
// 8 column-groups (g = blockIdx & 7) of 32 WGs. Group g owns batch columns
// {2g, 2g+1}. WG wl owns rows [wl*64, wl*64+64).
// K-SPLIT: wave wv owns K-chunk [wv*512, wv*512+512) of all 4 row-tiles;
// partials combined through LDS at the single barrier B2.
// ---------------------------------------------------------------------------
__global__ __launch_bounds__(256, 1) void hmm_persist(
    const float* __restrict__ alpha,
    const float* __restrict__ beta,
    const int*  __restrict__ ids,
    const float* __restrict__ gamma,
    ushort_t* __restrict__ Zbuf,
    float* __restrict__ out)
{
  const int w    = blockIdx.x;
  const int g    = w & 7;
  const int wl   = w >> 3;         // 0..31 within group -> row chunk
  const int c0   = g * 2;          // first batch column of group
  const int tid  = threadIdx.x;
  const int wv   = tid >> 6;       // wave 0..3 = K-chunk
  const int lane = tid & 63;
  const int lrow = lane & 15;
  const int quad = lane >> 4;

  __shared__ __align__(16) ushort_t zTf[2 * 2080];  // 2 cols x (2048+32 pad)
  __shared__ float ybuf[128];      // init only
  __shared__ float ipld[2][128];   // ip_rev[k]: [buf][row*2+col]
  __shared__ uint_t redm[2][4];    // [buf][wave] packed (c0max | c1max<<16)
  __shared__ __align__(16) float red[2][4][4][256]; // [buf][tile][wave][lane*4]
  __shared__ float fred[4][4];     // finalizer reduction scratch
  __shared__ float mh2[2];         // finalizer: mhat_255 per col

  ull_t* ZbA = (ull_t*)Zbuf;

  // ---- preload alpha A-fragments: rows wl*64+t*16+lrow, K=wv*512+kt*32 ----
  short8 afr[64];                  // [t*16 + kt]
  #pragma unroll
  for (int t = 0; t < 4; ++t) {
    #pragma unroll
    for (int kt = 0; kt < 16; ++kt) {
      const float* arow = alpha + (size_t)(wl * 64 + t * 16 + lrow) * Hh
                          + wv * 512 + kt * 32 + quad * 8;
      float4 f0 = *(const float4*)arow;
      float4 f1 = *(const float4*)(arow + 4);
      short8 fr;
      fr[0] = (short)f2b(f0.x); fr[1] = (short)f2b(f0.y);
      fr[2] = (short)f2b(f0.z); fr[3] = (short)f2b(f0.w);
      fr[4] = (short)f2b(f1.x); fr[5] = (short)f2b(f1.y);
      fr[6] = (short)f2b(f1.z); fr[7] = (short)f2b(f1.w);
      afr[t * 16 + kt] = fr;
    }
  }

  const int myc = tid & 1;                 // ip gather mapping for tid<128
  const int myr = wl * 64 + (tid >> 1);
  float ipreg = 0.f;

  // ---- init (k=0): y^0 = beta[:, ids[:,S-1]]; publish z~^0=exp(y^0) ----
  {
    if (tid < 128) {
      const int v = ids[(c0 + myc) * Ss + (Ss - 1)];
      float yv = beta[(size_t)myr * Vv + v];
      ybuf[tid] = yv;
      out[(size_t)myr * Bb + (c0 + myc)] = yv;   // ys[0][h][b]
    }
    __syncthreads();
    if (tid < 32) {
      const int c = tid >> 4, q = tid & 15;
      uint_t b0 = f2b(__expf(ybuf[(q * 4 + 0) * 2 + c]));
      uint_t b1 = f2b(__expf(ybuf[(q * 4 + 1) * 2 + c]));
      uint_t b2 = f2b(__expf(ybuf[(q * 4 + 2) * 2 + c]));
      uint_t b3 = f2b(__expf(ybuf[(q * 4 + 3) * 2 + c]));
      ull_t val = (ull_t)(b0 | (b1 << 16)) | ((ull_t)(b2 | (b3 << 16)) << 32);
      ST_REL(ZbA + (size_t)(c0 + c) * 512 + (wl * 16 + q), val);  // slot0, par0
    }
    if (tid < 128) {   // prefetch ip_rev[1]
      const int v1 = ids[(c0 + myc) * Ss + (Ss - 2)];
      ipreg = beta[(size_t)myr * Vv + v1];
    }
    __syncthreads();   // ybuf done before anything else reuses LDS region
  }

  // per-thread granule offsets: PAIRED mapping — thread owns granules
  // (2*lane, 2*lane+1) of its wave's K-chunk, per col. One 16B load each.
  const int hp  = wv * 128 + 2 * lane;     // first granule of the pair
  const size_t go0 = (size_t)c0 * 512 + hp;        // col c0  pair base
  const size_t go2 = (size_t)(c0 + 1) * 512 + hp;  // col c0+1 pair base

  float mprev = 0.f;               // mhat_{k-1} for col (lrow&1)
  const ushort_t* zbase = zTf + (lrow & 1) * 2080 + quad * 8;

  // epilogue geometry (thread-constant)
  const int  ec  = lrow;                           // batch col (act lanes)
  const int  rb  = wl * 64 + wv * 16 + quad * 4;   // output rows rb..rb+3
  const bool act = (lrow < 2);
  float pendy[4] = {0.f, 0.f, 0.f, 0.f};           // deferred out[] payload

  for (int k = 1; k < Ss; ++k) {
    const int   pb    = k & 1;     // LDS generation buffer
    const int   physR = (3 - ((k - 1) % 3)) % 3;
    const ull_t expS  = ((k - 1) & 1) ? SGN64 : 0ull;
    const size_t sb   = (size_t)physR * 8192;

    // ---- hoisted ip_rev[k+1] prefetch (address independent of z^{k-1}):
    //      the HBM gather completes under the poll wait ----
    float ipnext = 0.f;
    if (k < Ss - 1 && tid < 128) {
      const int v = ids[(c0 + myc) * Ss + (Ss - 2 - k)];
      ipnext = beta[(size_t)myr * Vv + v];
    }

    // ---- throttled paired poll: 2 x 16B system-scope loads ----
    ull_t z0, z1, z2, z3;
    {
      const ull_t* a01 = (const ull_t*)(ZbA + sb + go0);
      const ull_t* a23 = (const ull_t*)(ZbA + sb + go2);
      int r = 0;
      for (;;) {
        ullx2 pA, pB;
        asm volatile(
          "global_load_dwordx4 %0, %2, off sc0 sc1\n\t"
          "global_load_dwordx4 %1, %3, off sc0 sc1\n\t"
          "s_waitcnt vmcnt(0)"
          : "=&v"(pA), "=&v"(pB)
          : "v"(a01), "v"(a23)
          : "memory");
        z0 = pA.x; z1 = pA.y; z2 = pB.x; z3 = pB.y;
        if ((((z0 ^ expS) | (z1 ^ expS) | (z2 ^ expS) | (z3 ^ expS)) & SGN64) == 0ull)
          break;
        // escalate: 1 hot retry, then ~256cy, then ~1024cy between rounds
        if (r >= 3)      __builtin_amdgcn_s_sleep(16);
        else if (r >= 1) __builtin_amdgcn_s_sleep(4);
        ++r;
      }
    }

    // ---- stage into own wave-local zTf zone + per-col partial max ----
    uint_t m0, m1;
    {
      const ull_t u0 = z0 & MAG64, u1 = z1 & MAG64;
      const ull_t u2 = z2 & MAG64, u3 = z3 & MAG64;
      ullx2 w0; w0.x = u0; w0.y = u1;
      ullx2 w1; w1.x = u2; w1.y = u3;
      *(ullx2*)(zTf + wv * 512 + 8 * lane)        = w0;   // col0 zone, 16B
      *(ullx2*)(zTf + 2080 + wv * 512 + 8 * lane) = w1;   // col1 zone, 16B
      uint_t t0 = pkmax16(pkmax16((uint_t)u0, (uint_t)(u0 >> 32)),
                          pkmax16((uint_t)u1, (uint_t)(u1 >> 32)));
      uint_t t1 = pkmax16(pkmax16((uint_t)u2, (uint_t)(u2 >> 32)),
                          pkmax16((uint_t)u3, (uint_t)(u3 >> 32)));
      m0 = umaxu(t0 & 0xFFFFu, t0 >> 16);
      m1 = umaxu(t1 & 0xFFFFu, t1 >> 16);
    }
    if (tid < 128) ipld[pb][tid] = ipreg;
    ipreg = ipnext;                // hand over the hoisted prefetch
    uint_t pk = m0 | (m1 << 16);   // partial over rows [wv*512,(wv+1)*512)
    #pragma unroll
    for (int d = 1; d < 64; d <<= 1)
      pk = pkmax16(pk, (uint_t)__shfl_xor((int)pk, d));
    if (lane == 0) redm[pb][wv] = pk;

    // wave-local write->read ordering for zTf (no barrier here!)
    asm volatile("s_waitcnt lgkmcnt(0)" ::: "memory");
    __builtin_amdgcn_sched_barrier(0);

    // ---- MFMA, K-split: this wave's 512-wide K-chunk of all 4 row-tiles ----
    f32x4 acc0 = {0.f, 0.f, 0.f, 0.f}, acc1 = acc0, acc2 = acc0, acc3 = acc0;
    #pragma unroll
    for (int kt = 0; kt < 16; ++kt) {
      short8 bfr = *(const short8*)(zbase + (wv * 16 + kt) * 32);
      acc0 = __builtin_amdgcn_mfma_f32_16x16x32_bf16(afr[kt],      bfr, acc0, 0, 0, 0);
      acc1 = __builtin_amdgcn_mfma_f32_16x16x32_bf16(afr[16 + kt], bfr, acc1, 0, 0, 0);
      acc2 = __builtin_amdgcn_mfma_f32_16x16x32_bf16(afr[32 + kt], bfr, acc2, 0, 0, 0);
      acc3 = __builtin_amdgcn_mfma_f32_16x16x32_bf16(afr[48 + kt], bfr, acc3, 0, 0, 0);
    }

    // ---- cross-wave K-reduction through LDS (double-buffered) ----
    if (wv != 0) *(f32x4*)&red[pb][0][wv][lane * 4] = acc0;
    if (wv != 1) *(f32x4*)&red[pb][1][wv][lane * 4] = acc1;
    if (wv != 2) *(f32x4*)&red[pb][2][wv][lane * 4] = acc2;
    if (wv != 3) *(f32x4*)&red[pb][3][wv][lane * 4] = acc3;
    __syncthreads();                                   // B2 — the ONLY barrier
    f32x4 sf = acc0;                                   // static own-tile select
    if (wv == 1) sf = acc1;
    else if (wv == 2) sf = acc2;
    else if (wv == 3) sf = acc3;
    #pragma unroll
    for (int v = 0; v < 4; ++v)
      if (v != wv) sf += *(const f32x4*)&red[pb][wv][v][lane * 4];

    // ---- combine col max (fixed order -> bit-identical across WGs) ----
    const uint_t rr = pkmax16(pkmax16(redm[pb][0], redm[pb][1]),
                              pkmax16(redm[pb][2], redm[pb][3]));
    const uint_t mm = (lrow & 1) ? (rr >> 16) : (rr & 0xFFFFu);
    const float lmax = __logf(b2f_u(mm << 16));
    float ipv[4];
    #pragma unroll
    for (int i = 0; i < 4; ++i)
      ipv[i] = ipld[pb][(wv * 16 + quad * 4 + i) * 2 + (lrow & 1)];

    // ---- epilogue: y = log(sum) + mhat_{k-1} + ip; publish FIRST ----
    const float mnew = mprev + lmax;       // mhat_k
    if (act) {
      float yv4[4];
      #pragma unroll
      for (int i = 0; i < 4; ++i)
        yv4[i] = __logf(sf[i]) + mprev + ipv[i];
      uint_t o0 = (uint_t)f2b(__expf(yv4[0] - mnew)) |
                  ((uint_t)f2b(__expf(yv4[1] - mnew)) << 16);
      uint_t o1 = (uint_t)f2b(__expf(yv4[2] - mnew)) |
                  ((uint_t)f2b(__expf(yv4[3] - mnew)) << 16);
      const int   physW = (3 - (k % 3)) % 3;
      const ull_t orS   = (k & 1) ? SGN64 : 0ull;
      ST_REL(ZbA + (size_t)physW * 8192 + (size_t)(c0 + ec) * 512 + (rb >> 2),
             ((ull_t)o0 | ((ull_t)o1 << 32)) | orS);
      // deferred ys[k-1] AFTER publish: a full step (~10K cy) to ack
      #pragma unroll
      for (int i = 0; i < 4; ++i)
        out[(size_t)(k - 1) * (Hh * Bb) + (size_t)(rb + i) * Bb + (c0 + ec)] = pendy[i];
      #pragma unroll
      for (int i = 0; i < 4; ++i) pendy[i] = yv4[i];
    }
    mprev = mnew;
    // no second barrier: zTf zones are wave-local; red/redm/ipld generation
    // pb is read post-B2(k) and next written pre-B2(k+2), with B2(k+1)
    // separating readers from writers.
  }

  // ---- flush last deferred ys[255] ----
  if (act) {
    #pragma unroll
    for (int i = 0; i < 4; ++i)
      out[(size_t)(Ss - 1) * (Hh * Bb) + (size_t)(rb + i) * Bb + (c0 + ec)] = pendy[i];
  }

  // ---- fused finalizer: leader WG of each group computes final[c0..c0+1] --
  // final[c] = log(sum_h e^{g_h-gm} z~255_{c,h}) - log(sum_h e^{g_h-gm}) + mhat255_c
  // z~^255 lives in slot phys(255%3)=0, parity 1 — published above.
  if (wl == 0) {
    if (tid < 2) mh2[tid] = mprev;   // tid0: lrow0 -> col c0; tid1 -> c0+1
    __syncthreads();
    // gamma rows for this thread's paired granules: col rows
    //   z0 -> [wv*512+8*lane, +4), z1 -> [+4, +8) (same for z2/z3 on col+1)
    float4 ga = *(const float4*)(gamma + wv * 512 + 8 * lane);
    float4 gb = *(const float4*)(gamma + wv * 512 + 8 * lane + 4);
    float gmx = fmaxf(fmaxf(fmaxf(ga.x, ga.y), fmaxf(ga.z, ga.w)),
                      fmaxf(fmaxf(gb.x, gb.y), fmaxf(gb.z, gb.w)));
    #pragma unroll
    for (int d = 1; d < 64; d <<= 1) gmx = fmaxf(gmx, __shfl_xor(gmx, d));
    if (lane == 0) fred[wv][0] = gmx;
    __syncthreads();
    const float gm = fmaxf(fmaxf(fred[0][0], fred[1][0]),
                           fmaxf(fred[2][0], fred[3][0]));
    float wga[4], wgb[4];
    wga[0] = __expf(ga.x - gm); wga[1] = __expf(ga.y - gm);
    wga[2] = __expf(ga.z - gm); wga[3] = __expf(ga.w - gm);
    wgb[0] = __expf(gb.x - gm); wgb[1] = __expf(gb.y - gm);
    wgb[2] = __expf(gb.z - gm); wgb[3] = __expf(gb.w - gm);
    float s1 = ((wga[0] + wga[1]) + (wga[2] + wga[3])) +
               ((wgb[0] + wgb[1]) + (wgb[2] + wgb[3]));
    // poll z~^255 (paired-granule mapping; data published above)
    ull_t z0 = LD_REL(ZbA + go0), z1 = LD_REL(ZbA + go0 + 1);
    ull_t z2 = LD_REL(ZbA + go2), z3 = LD_REL(ZbA + go2 + 1);
    while ((((z0 ^ SGN64) | (z1 ^ SGN64) | (z2 ^ SGN64) | (z3 ^ SGN64)) & SGN64) != 0ull) {
      if ((z0 & SGN64) != SGN64) z0 = LD_REL(ZbA + go0);
      if ((z1 & SGN64) != SGN64) z1 = LD_REL(ZbA + go0 + 1);
      if ((z2 & SGN64) != SGN64) z2 = LD_REL(ZbA + go2);
      if ((z3 & SGN64) != SGN64) z3 = LD_REL(ZbA + go2 + 1);
    }
    float s2a = 0.f, s2b = 0.f;
    #pragma unroll
    for (int i = 0; i < 4; ++i) {
      s2a += wga[i] * b2f_u(((uint_t)(z0 >> (16 * i)) & 0x7FFFu) << 16);
      s2a += wgb[i] * b2f_u(((uint_t)(z1 >> (16 * i)) & 0x7FFFu) << 16);
      s2b += wga[i] * b2f_u(((uint_t)(z2 >> (16 * i)) & 0x7FFFu) << 16);
      s2b += wgb[i] * b2f_u(((uint_t)(z3 >> (16 * i)) & 0x7FFFu) << 16);
    }
    #pragma unroll
    for (int d = 1; d < 64; d <<= 1) {
      s1  += __shfl_xor(s1, d);
      s2a += __shfl_xor(s2a, d);
      s2b += __shfl_xor(s2b, d);
    }
    if (lane == 0) { fred[wv][1] = s1; fred[wv][2] = s2a; fred[wv][3] = s2b; }
    __syncthreads();
    if (tid == 0) {
      float S1 = ((fred[0][1] + fred[1][1]) + (fred[2][1] + fred[3][1]));
      float Sa = ((fred[0][2] + fred[1][2]) + (fred[2][2] + fred[3][2]));
      float Sb = ((fred[0][3] + fred[1][3]) + (fred[2][3] + fred[3][3]));
      const float ls1 = __logf(S1);
      out[(size_t)Ss * Hh * Bb + c0]     = __logf(Sa) - ls1 + mh2[0];
      out[(size_t)Ss * Hh * Bb + c0 + 1] = __logf(Sb) - ls1 + mh2[1];
    }
  }
}

// ---------------------------------------------------------------------------
extern "C" void kernel_launch(void* const* d_in, const int* in_sizes, int n_in,
                              void* d_out, int out_size, void* d_ws, size_t ws_size,
                              hipStream_t stream) {
  (void)in_sizes; (void)n_in; (void)out_size;
  const int*   ids   = (const int*)d_in[0];
  const float* alpha = (const float*)d_in[1];
  const float* beta  = (const float*)d_in[2];
  const float* gamma = (const float*)d_in[3];
  float* out = (float*)d_out;
  char* ws = (char*)d_ws;

  if (ws_size < WS_NEED) return;   // clean fail rather than OOB

  ushort_t* Zbuf = (ushort_t*)ws;

  // Epoch-pattern init: slots 0,1 -> sign=1 (0x80), slot 2 -> sign=0.
  // Each slot's first poll expects the opposite parity, so consumers block
  // until real data lands; also scrubs the previous launch's leftovers.
  hipMemsetAsync(ws, 0x80, 2 * Z_SLOT, stream);
  hipMemsetAsync(ws + 2 * Z_SLOT, 0x00, Z_SLOT, stream);

  {
    const float* a_alpha = alpha;
    const float* a_beta  = beta;
    const int*   a_ids   = ids;
    const float* a_gamma = gamma;
    ushort_t* a_z = Zbuf;  float* a_out = out;
    void* args[] = {(void*)&a_alpha, (void*)&a_beta, (void*)&a_ids,
                    (void*)&a_gamma, (void*)&a_z, (void*)&a_out};
    hipError_t e = hipLaunchCooperativeKernel((const void*)hmm_persist,
                                              dim3(256), dim3(256), args, 0, stream);
    if (e != hipSuccess) {
      hipLaunchKernelGGL(hmm_persist, dim3(256), dim3(256), 0, stream,
                         alpha, beta, ids, gamma, Zbuf, out);
    }
  }
}